// Round 4
// baseline (1046.641 us; speedup 1.0000x reference)
//
#include <hip/hip_runtime.h>
#include <hip/hip_bf16.h>

#define E_EDGES 1000000

typedef __attribute__((ext_vector_type(8))) short bf16x8;
typedef __attribute__((ext_vector_type(4))) float f32x4;

__device__ __forceinline__ short f2bf(float f) {
    union { __hip_bfloat16 b; short s; } u;
    u.b = __float2bfloat16(f);
    return u.s;
}
__device__ __forceinline__ bf16x8 pack8(float4 a, float4 b) {
    bf16x8 r;
    r[0]=f2bf(a.x); r[1]=f2bf(a.y); r[2]=f2bf(a.z); r[3]=f2bf(a.w);
    r[4]=f2bf(b.x); r[5]=f2bf(b.y); r[6]=f2bf(b.z); r[7]=f2bf(b.w);
    return r;
}
__device__ __forceinline__ float4 ld4(const float* p) {
    return *reinterpret_cast<const float4*>(p);
}
__device__ __forceinline__ float silu1(float x) { return x / (1.f + __expf(-x)); }
__device__ __forceinline__ float tanh1(float x) {
    float e = __expf(2.f * x);
    return 1.f - 2.f / (e + 1.f);
}

// +b_in then LayerNorm over 128 cols; row lives in a 16-lane quarter-group.
__device__ __forceinline__ void ln_inplace(f32x4 (&aX)[8], const float* __restrict__ bin, int ln) {
    #pragma unroll
    for (int nt = 0; nt < 8; ++nt) {
        float bv = bin[(nt<<4) + ln];
        #pragma unroll
        for (int r = 0; r < 4; ++r) aX[nt][r] += bv;
    }
    #pragma unroll
    for (int r = 0; r < 4; ++r) {
        float p = 0.f, q = 0.f;
        #pragma unroll
        for (int nt = 0; nt < 8; ++nt) { float x = aX[nt][r]; p += x; q += x*x; }
        #pragma unroll
        for (int d2 = 1; d2 < 16; d2 <<= 1) { p += __shfl_xor(p, d2); q += __shfl_xor(q, d2); }
        float mean = p * 0.0078125f;
        float var  = q * 0.0078125f - mean * mean;
        float rstd = rsqrtf(var + 1e-6f);
        #pragma unroll
        for (int nt = 0; nt < 8; ++nt)
            aX[nt][r] = (aX[nt][r] - mean) * rstd;
    }
}

// ---------------- weight pre-pack: f32 [K][N] -> bf16 MFMA B-fragments ----------
// fragment (nt, ks): 64 lanes x 8 bf16, lane l slot j  <- W[ks*32 + 8*(l>>4)+j][nt*16 + (l&15)]
__global__ void pack_weights_kernel(const float* __restrict__ Wt,
                                    const float* __restrict__ Win,
                                    const float* __restrict__ W1,
                                    const float* __restrict__ W2,
                                    short* __restrict__ ws)
{
    int gid = blockIdx.x * 256 + threadIdx.x;
    const float* src; int K, Nw, local; short* dst;
    if      (gid <  32768) { src = Wt;  K = 128; Nw = 256; local = gid;          dst = ws;         }
    else if (gid <  81920) { src = Win; K = 384; Nw = 128; local = gid -  32768; dst = ws + 32768; }
    else if (gid <  98304) { src = W1;  K = 128; Nw = 128; local = gid -  81920; dst = ws + 81920; }
    else if (gid < 100352) { src = W2;  K = 128; Nw =   4; local = gid -  98304; dst = ws + 98304; }
    else return;
    int KS     = K >> 5;
    int frag   = local >> 9;
    int within = local & 511;
    int l  = within >> 3, j = within & 7;
    int nt = frag / KS,  ks = frag - nt * KS;
    int k  = ks * 32 + ((l >> 4) << 3) + j;
    int n  = nt * 16 + (l & 15);
    float v = (n < Nw) ? src[k * Nw + n] : 0.0f;   // zero-pad W2 cols 4..15
    dst[local] = f2bf(v);
}

// ------- fused edge kernel: barrier-free, one wave = 32 edges (2 jammed M-tiles) ----
__global__ __launch_bounds__(128, 3)
void edge_kernel(const float* __restrict__ h,
                 const float* __restrict__ pos,
                 const float* __restrict__ ea,
                 const float* __restrict__ dst_f,
                 const float* __restrict__ temb,
                 const float* __restrict__ adj,
                 const float* __restrict__ btime,
                 const float* __restrict__ bin,
                 const float* __restrict__ b1,
                 const float* __restrict__ cscale,
                 const int*   __restrict__ ei,
                 const short* __restrict__ ws,
                 float* __restrict__ out)
{
    __shared__ short Tb[2][32 * 136];     // per-wave transpose buffer (8704 B each)
    __shared__ float sCd[2][3][32];
    __shared__ float sAdj[2][3][32];
    __shared__ int   sIr[2][32];

    const int tid = threadIdx.x;
    const int w   = tid >> 6;
    const int l   = tid & 63;
    const int ln  = l & 15;
    const int lg  = l >> 4;
    const int kb  = lg << 3;              // this lane's k-octet base within a 32-k step
    const int e0  = (blockIdx.x * 2 + w) * 32;
    const int em0 = e0 + ln;              // tile-0 A-row edge
    const int em1 = e0 + 16 + ln;         // tile-1 A-row edge

    const int ir0 = ei[em0];
    const int ir1 = ei[em1];
    const int ic0 = ei[E_EDGES + em0];
    const int ic1 = ei[E_EDGES + em1];

    // per-edge geometry: lanes 0..31 handle the wave's 32 edges
    if (l < 32) {
        int e  = e0 + l;
        int ir = ei[e];
        int ic = ei[E_EDGES + e];
        sIr[w][l] = ir;
        float dx = pos[ir*3+0] - pos[ic*3+0];
        float dy = pos[ir*3+1] - pos[ic*3+1];
        float dz = pos[ir*3+2] - pos[ic*3+2];
        float nrm = sqrtf(dx*dx + dy*dy + dz*dz);
        float s = cscale[0] / fmaxf(nrm, 1e-8f);
        sCd[w][0][l] = dx * s;
        sCd[w][1][l] = dy * s;
        sCd[w][2][l] = dz * s;
        sAdj[w][0][l] = adj[e*3+0];
        sAdj[w][1][l] = adj[e*3+1];
        sAdj[w][2][l] = adj[e*3+2];
    }

    const bf16x8* wtP  = reinterpret_cast<const bf16x8*>(ws);          // W_time: 16nt x 4ks
    const bf16x8* winP = reinterpret_cast<const bf16x8*>(ws + 32768);  // W_in:    8nt x 12ks
    const bf16x8* w1P  = reinterpret_cast<const bf16x8*>(ws + 81920);  // W1:      8nt x 4ks
    const bf16x8* w2P  = reinterpret_cast<const bf16x8*>(ws + 98304);  // W2pad:   1nt x 4ks

    // ---- X = h_input @ W_in : A-frags global->reg, each W-frag feeds 2 MFMAs ----
    f32x4 accX0[8], accX1[8];
    #pragma unroll
    for (int i = 0; i < 8; ++i) {
        accX0[i] = (f32x4){0.f,0.f,0.f,0.f};
        accX1[i] = (f32x4){0.f,0.f,0.f,0.f};
    }

    #pragma unroll
    for (int seg = 0; seg < 3; ++seg) {
        bf16x8 af0[4], af1[4];
        #pragma unroll
        for (int ks = 0; ks < 4; ++ks) {
            int k0 = (ks << 5) + kb;
            const float *q0, *q1;
            if (seg == 0)      { q0 = h + (long)ir0 * 128 + k0; q1 = h + (long)ir1 * 128 + k0; }
            else if (seg == 1) { q0 = h + (long)ic0 * 128 + k0; q1 = h + (long)ic1 * 128 + k0; }
            else {
                q0 = (k0 < 64) ? (ea + (long)em0 * 64 + k0) : (dst_f + (long)em0 * 64 + (k0 - 64));
                q1 = (k0 < 64) ? (ea + (long)em1 * 64 + k0) : (dst_f + (long)em1 * 64 + (k0 - 64));
            }
            af0[ks] = pack8(ld4(q0), ld4(q0 + 4));
            af1[ks] = pack8(ld4(q1), ld4(q1 + 4));
        }
        #pragma unroll
        for (int nt = 0; nt < 8; ++nt)
            #pragma unroll
            for (int ks = 0; ks < 4; ++ks) {
                bf16x8 b = winP[(nt*12 + (seg<<2) + ks)*64 + l];
                accX0[nt] = __builtin_amdgcn_mfma_f32_16x16x32_bf16(af0[ks], b, accX0[nt], 0, 0, 0);
                accX1[nt] = __builtin_amdgcn_mfma_f32_16x16x32_bf16(af1[ks], b, accX1[nt], 0, 0, 0);
            }
    }

    // ---- bias + LayerNorm, per tile ----
    ln_inplace(accX0, bin, ln);
    ln_inplace(accX1, bin, ln);

    // ---- FiLM: T computed nt-sequentially, fragment shared across tiles ----
    bf16x8 ttf0[4], ttf1[4];
    #pragma unroll
    for (int ks = 0; ks < 4; ++ks) {
        const float* q0 = temb + (long)em0 * 128 + (ks << 5) + kb;
        const float* q1 = temb + (long)em1 * 128 + (ks << 5) + kb;
        float4 a0 = ld4(q0), b0 = ld4(q0 + 4);
        float4 a1 = ld4(q1), b1v = ld4(q1 + 4);
        a0.x=silu1(a0.x); a0.y=silu1(a0.y); a0.z=silu1(a0.z); a0.w=silu1(a0.w);
        b0.x=silu1(b0.x); b0.y=silu1(b0.y); b0.z=silu1(b0.z); b0.w=silu1(b0.w);
        a1.x=silu1(a1.x); a1.y=silu1(a1.y); a1.z=silu1(a1.z); a1.w=silu1(a1.w);
        b1v.x=silu1(b1v.x); b1v.y=silu1(b1v.y); b1v.z=silu1(b1v.z); b1v.w=silu1(b1v.w);
        ttf0[ks] = pack8(a0, b0);
        ttf1[ks] = pack8(a1, b1v);
    }
    #pragma unroll
    for (int j = 0; j < 8; ++j) {        // scale half: W_time col blocks 8..15
        f32x4 t0 = (f32x4){0.f,0.f,0.f,0.f};
        f32x4 t1 = (f32x4){0.f,0.f,0.f,0.f};
        #pragma unroll
        for (int ks = 0; ks < 4; ++ks) {
            bf16x8 b = wtP[(((8+j)<<2) + ks)*64 + l];
            t0 = __builtin_amdgcn_mfma_f32_16x16x32_bf16(ttf0[ks], b, t0, 0, 0, 0);
            t1 = __builtin_amdgcn_mfma_f32_16x16x32_bf16(ttf1[ks], b, t1, 0, 0, 0);
        }
        float bsc = btime[128 + (j<<4) + ln];
        #pragma unroll
        for (int r = 0; r < 4; ++r) {
            accX0[j][r] *= (1.f + t0[r] + bsc);
            accX1[j][r] *= (1.f + t1[r] + bsc);
        }
    }
    #pragma unroll
    for (int j = 0; j < 8; ++j) {        // shift half: W_time col blocks 0..7
        f32x4 t0 = (f32x4){0.f,0.f,0.f,0.f};
        f32x4 t1 = (f32x4){0.f,0.f,0.f,0.f};
        #pragma unroll
        for (int ks = 0; ks < 4; ++ks) {
            bf16x8 b = wtP[((j<<2) + ks)*64 + l];
            t0 = __builtin_amdgcn_mfma_f32_16x16x32_bf16(ttf0[ks], b, t0, 0, 0, 0);
            t1 = __builtin_amdgcn_mfma_f32_16x16x32_bf16(ttf1[ks], b, t1, 0, 0, 0);
        }
        float bsh = btime[(j<<4) + ln];
        #pragma unroll
        for (int r = 0; r < 4; ++r) {
            accX0[j][r] += t0[r] + bsh;
            accX1[j][r] += t1[r] + bsh;
        }
    }

    // ---- transpose inv (C-layout -> A-layout) through per-wave LDS ----
    short* tb = &Tb[w][0];
    #pragma unroll
    for (int nt = 0; nt < 8; ++nt)
        #pragma unroll
        for (int r = 0; r < 4; ++r) {
            tb[((lg<<2) + r)*136      + (nt<<4) + ln] = f2bf(accX0[nt][r]);
            tb[(16 + (lg<<2) + r)*136 + (nt<<4) + ln] = f2bf(accX1[nt][r]);
        }
    bf16x8 iaf0[4], iaf1[4];
    #pragma unroll
    for (int ks = 0; ks < 4; ++ks) {
        iaf0[ks] = *reinterpret_cast<const bf16x8*>(&tb[ln*136        + (ks<<5) + kb]);
        iaf1[ks] = *reinterpret_cast<const bf16x8*>(&tb[(16+ln)*136   + (ks<<5) + kb]);
    }

    // ---- y = silu(inv @ W1 + b1), transpose back through same buffer ----
    f32x4 accY0[8], accY1[8];
    #pragma unroll
    for (int i = 0; i < 8; ++i) {
        accY0[i] = (f32x4){0.f,0.f,0.f,0.f};
        accY1[i] = (f32x4){0.f,0.f,0.f,0.f};
    }
    #pragma unroll
    for (int nt = 0; nt < 8; ++nt)
        #pragma unroll
        for (int ks = 0; ks < 4; ++ks) {
            bf16x8 b = w1P[((nt<<2) + ks)*64 + l];
            accY0[nt] = __builtin_amdgcn_mfma_f32_16x16x32_bf16(iaf0[ks], b, accY0[nt], 0, 0, 0);
            accY1[nt] = __builtin_amdgcn_mfma_f32_16x16x32_bf16(iaf1[ks], b, accY1[nt], 0, 0, 0);
        }
    #pragma unroll
    for (int nt = 0; nt < 8; ++nt) {
        float bv = b1[(nt<<4) + ln];
        #pragma unroll
        for (int r = 0; r < 4; ++r) {
            tb[((lg<<2) + r)*136      + (nt<<4) + ln] = f2bf(silu1(accY0[nt][r] + bv));
            tb[(16 + (lg<<2) + r)*136 + (nt<<4) + ln] = f2bf(silu1(accY1[nt][r] + bv));
        }
    }
    bf16x8 yaf0[4], yaf1[4];
    #pragma unroll
    for (int ks = 0; ks < 4; ++ks) {
        yaf0[ks] = *reinterpret_cast<const bf16x8*>(&tb[ln*136      + (ks<<5) + kb]);
        yaf1[ks] = *reinterpret_cast<const bf16x8*>(&tb[(16+ln)*136 + (ks<<5) + kb]);
    }

    // ---- z = tanh(y @ W2) ; per-edge scalar ; atomic scatter ----
    f32x4 accZ0 = (f32x4){0.f,0.f,0.f,0.f};
    f32x4 accZ1 = (f32x4){0.f,0.f,0.f,0.f};
    #pragma unroll
    for (int ks = 0; ks < 4; ++ks) {
        bf16x8 b = w2P[ks*64 + l];
        accZ0 = __builtin_amdgcn_mfma_f32_16x16x32_bf16(yaf0[ks], b, accZ0, 0, 0, 0);
        accZ1 = __builtin_amdgcn_mfma_f32_16x16x32_bf16(yaf1[ks], b, accZ1, 0, 0, 0);
    }
    #pragma unroll
    for (int r = 0; r < 4; ++r) {
        {   // tile 0
            int   m = (lg<<2) + r;
            float z = tanh1(accZ0[r]);
            float wt = (ln == 0) ? 1.0f : ((ln < 4) ? sAdj[w][ln-1][m] : 0.0f);
            float v = z * wt;
            v += __shfl_xor(v, 1);
            v += __shfl_xor(v, 2);
            v += __shfl_xor(v, 4);
            v += __shfl_xor(v, 8);
            float s = v * 0.25f;
            if (ln < 3) atomicAdd(&out[(long)sIr[w][m]*3 + ln], sCd[w][ln][m] * s);
        }
        {   // tile 1
            int   m = 16 + (lg<<2) + r;
            float z = tanh1(accZ1[r]);
            float wt = (ln == 0) ? 1.0f : ((ln < 4) ? sAdj[w][ln-1][m] : 0.0f);
            float v = z * wt;
            v += __shfl_xor(v, 1);
            v += __shfl_xor(v, 2);
            v += __shfl_xor(v, 4);
            v += __shfl_xor(v, 8);
            float s = v * 0.25f;
            if (ln < 3) atomicAdd(&out[(long)sIr[w][m]*3 + ln], sCd[w][ln][m] * s);
        }
    }
}

extern "C" void kernel_launch(void* const* d_in, const int* in_sizes, int n_in,
                              void* d_out, int out_size, void* d_ws, size_t ws_size,
                              hipStream_t stream) {
    const float* h     = (const float*)d_in[0];
    const float* pos   = (const float*)d_in[1];
    const float* ea    = (const float*)d_in[2];
    const float* dist  = (const float*)d_in[3];
    const float* temb  = (const float*)d_in[4];
    const float* adj   = (const float*)d_in[5];
    const float* Wt    = (const float*)d_in[6];
    const float* bt    = (const float*)d_in[7];
    const float* Win   = (const float*)d_in[8];
    const float* bin   = (const float*)d_in[9];
    const float* W1    = (const float*)d_in[10];
    const float* b1    = (const float*)d_in[11];
    const float* W2    = (const float*)d_in[12];
    const float* cs    = (const float*)d_in[13];
    const int*   ei    = (const int*)d_in[14];
    float*       out   = (float*)d_out;
    short*       ws    = (short*)d_ws;

    pack_weights_kernel<<<(100352 + 255) / 256, 256, 0, stream>>>(Wt, Win, W1, W2, ws);
    hipMemcpyAsync(out, pos, (size_t)out_size * sizeof(float),
                   hipMemcpyDeviceToDevice, stream);
    edge_kernel<<<E_EDGES / 64, 128, 0, stream>>>(h, pos, ea, dist, temb, adj,
                                                  bt, bin, b1, cs, ei, ws, out);
}

// Round 5
// 751.748 us; speedup vs baseline: 1.3923x; 1.3923x over previous
//
#include <hip/hip_runtime.h>
#include <hip/hip_bf16.h>

#define E_EDGES 1000000

typedef __attribute__((ext_vector_type(8))) short bf16x8;
typedef __attribute__((ext_vector_type(4))) float f32x4;

#define WAITV(N) asm volatile("s_waitcnt vmcnt(" #N ")" ::: "memory")

__device__ __forceinline__ short f2bf(float f) {
    union { __hip_bfloat16 b; short s; } u;
    u.b = __float2bfloat16(f);
    return u.s;
}
__device__ __forceinline__ bf16x8 pack8(float4 a, float4 b) {
    bf16x8 r;
    r[0]=f2bf(a.x); r[1]=f2bf(a.y); r[2]=f2bf(a.z); r[3]=f2bf(a.w);
    r[4]=f2bf(b.x); r[5]=f2bf(b.y); r[6]=f2bf(b.z); r[7]=f2bf(b.w);
    return r;
}
__device__ __forceinline__ float4 ld4(const float* p) {
    return *reinterpret_cast<const float4*>(p);
}
__device__ __forceinline__ float silu1(float x) { return x / (1.f + __expf(-x)); }
__device__ __forceinline__ float tanh1(float x) {
    float e = __expf(2.f * x);
    return 1.f - 2.f / (e + 1.f);
}

// ---------------- weight pre-pack: f32 -> bf16 frags in CHUNK-LINEAR order ------
// 196 frags of 512 shorts; frag f element (l*8+j) = W[k(l,j)][n(l)].
// chunk = 8 consecutive frags, consumed in order by the edge kernel:
//   frags 0..95   : W_in,  chunk cs=seg*4+ks (12 chunks), within: nt=0..7
//   frags 96..159 : W_time, chunk ch (8): ch<4 -> scale cols j=8+2ch+jj; else shift j=2(ch-4)+jj; within: jj*4+ks
//   frags 160..191: W1, chunk ch (4): nt=2ch+(sub>>2), ks=sub&3
//   frags 192..195: W2 padded, ks=0..3
__global__ void pack_weights_kernel(const float* __restrict__ Wt,
                                    const float* __restrict__ Win,
                                    const float* __restrict__ W1,
                                    const float* __restrict__ W2,
                                    short* __restrict__ ws)
{
    int gid = blockIdx.x * 256 + threadIdx.x;
    if (gid >= 196 * 512) return;
    int frag = gid >> 9, within = gid & 511;
    int l = within >> 3, j = within & 7;
    int lg = l >> 4, ln = l & 15;
    int krow = (lg << 3) + j;              // k offset within a 32-wide k-step
    float v;
    if (frag < 96) {
        int cs = frag >> 3, nt = frag & 7;
        int seg = cs >> 2, ks = cs & 3;
        int k = seg * 128 + ks * 32 + krow;
        v = Win[k * 128 + nt * 16 + ln];
    } else if (frag < 160) {
        int t = frag - 96, ch = t >> 3, sub = t & 7;
        int jj = sub >> 2, ks = sub & 3;
        int jcol = (ch < 4) ? (8 + 2 * ch + jj) : (2 * (ch - 4) + jj);
        int k = ks * 32 + krow;
        v = Wt[k * 256 + jcol * 16 + ln];
    } else if (frag < 192) {
        int t = frag - 160, ch = t >> 3, sub = t & 7;
        int nt = 2 * ch + (sub >> 2), ks = sub & 3;
        int k = ks * 32 + krow;
        v = W1[k * 128 + nt * 16 + ln];
    } else {
        int ks = frag - 192;
        int k = ks * 32 + krow;
        v = (ln < 4) ? W2[k * 4 + ln] : 0.0f;
    }
    ws[gid] = f2bf(v);
}

// ---- async staging: one global_load_lds per fragment (64 lanes x 16 B), 0 VGPRs ----
__device__ __forceinline__ void stage_frag(const short* gsrc, short* ldst) {
    __builtin_amdgcn_global_load_lds(
        (const __attribute__((address_space(1))) void*)gsrc,
        (__attribute__((address_space(3))) void*)ldst, 16, 0, 0);
}

// +b_in then LayerNorm over 128 cols; row lives in a 16-lane quarter-group.
__device__ __forceinline__ void ln_inplace(f32x4 (&aX)[8], const float* __restrict__ bin, int ln) {
    #pragma unroll
    for (int nt = 0; nt < 8; ++nt) {
        float bv = bin[(nt<<4) + ln];
        #pragma unroll
        for (int r = 0; r < 4; ++r) aX[nt][r] += bv;
    }
    #pragma unroll
    for (int r = 0; r < 4; ++r) {
        float p = 0.f, q = 0.f;
        #pragma unroll
        for (int nt = 0; nt < 8; ++nt) { float x = aX[nt][r]; p += x; q += x*x; }
        #pragma unroll
        for (int d2 = 1; d2 < 16; d2 <<= 1) { p += __shfl_xor(p, d2); q += __shfl_xor(q, d2); }
        float mean = p * 0.0078125f;
        float var  = q * 0.0078125f - mean * mean;
        float rstd = rsqrtf(var + 1e-6f);
        #pragma unroll
        for (int nt = 0; nt < 8; ++nt)
            aX[nt][r] = (aX[nt][r] - mean) * rstd;
    }
}

// ------ fused edge kernel: 1 wave = 1 block = 32 edges; async LDS weight pipeline ------
__global__ __launch_bounds__(64, 2)
void edge_kernel(const float* __restrict__ h,
                 const float* __restrict__ pos,
                 const float* __restrict__ ea,
                 const float* __restrict__ dst_f,
                 const float* __restrict__ temb,
                 const float* __restrict__ adj,
                 const float* __restrict__ btime,
                 const float* __restrict__ bin,
                 const float* __restrict__ b1,
                 const float* __restrict__ cscale,
                 const int*   __restrict__ ei,
                 const short* __restrict__ ws,
                 float* __restrict__ out)
{
    __shared__ __align__(16) short Wb[2][4096];   // 2 x 8 KB weight chunk dbuf
    __shared__ __align__(16) short Tb[32 * 136];  // transpose buffer (8704 B)
    __shared__ int   sIr[32];
    __shared__ float sCd[3][32];
    __shared__ float sAdj[3][32];

    const int l  = threadIdx.x;
    const int ln = l & 15;
    const int lg = l >> 4;
    const int kb = lg << 3;
    const int e0  = blockIdx.x << 5;
    const int em0 = e0 + ln;
    const int em1 = e0 + 16 + ln;

    const int ir0 = ei[em0];
    const int ir1 = ei[em1];
    const int ic0 = ei[E_EDGES + em0];
    const int ic1 = ei[E_EDGES + em1];

    // chunk issue helper: chunk p -> Wb[p&1]
    #define STAGE8(p) { \
        const short* g_ = ws + (p) * 4096 + l * 8; \
        short* d_ = &Wb[(p) & 1][0]; \
        _Pragma("unroll") \
        for (int f_ = 0; f_ < 8; ++f_) stage_frag(g_ + f_ * 512, d_ + f_ * 512); }
    #define STAGE4(p) { \
        const short* g_ = ws + (p) * 4096 + l * 8; \
        short* d_ = &Wb[(p) & 1][0]; \
        _Pragma("unroll") \
        for (int f_ = 0; f_ < 4; ++f_) stage_frag(g_ + f_ * 512, d_ + f_ * 512); }

    // ---- prologue: A-operands for seg0 + first weight chunk ----
    float4 Ab[2][2][8];     // [parity][tile][slot]; all indices static after unroll
    #pragma unroll
    for (int ks = 0; ks < 4; ++ks) {
        Ab[0][0][2*ks]   = ld4(h + (long)ir0 * 128 + ks*32 + kb);
        Ab[0][0][2*ks+1] = ld4(h + (long)ir0 * 128 + ks*32 + kb + 4);
        Ab[0][1][2*ks]   = ld4(h + (long)ir1 * 128 + ks*32 + kb);
        Ab[0][1][2*ks+1] = ld4(h + (long)ir1 * 128 + ks*32 + kb + 4);
    }
    STAGE8(0);

    // per-edge geometry (lanes 0..31), wave-local LDS, no barrier needed
    if (l < 32) {
        int e  = e0 + l;
        int ir = ei[e];
        int ic = ei[E_EDGES + e];
        sIr[l] = ir;
        float dx = pos[ir*3+0] - pos[ic*3+0];
        float dy = pos[ir*3+1] - pos[ic*3+1];
        float dz = pos[ir*3+2] - pos[ic*3+2];
        float nrm = sqrtf(dx*dx + dy*dy + dz*dz);
        float s = cscale[0] / fmaxf(nrm, 1e-8f);
        sCd[0][l] = dx * s;
        sCd[1][l] = dy * s;
        sCd[2][l] = dz * s;
        sAdj[0][l] = adj[e*3+0];
        sAdj[1][l] = adj[e*3+1];
        sAdj[2][l] = adj[e*3+2];
    }

    f32x4 accX0[8], accX1[8];
    #pragma unroll
    for (int i = 0; i < 8; ++i) {
        accX0[i] = (f32x4){0.f,0.f,0.f,0.f};
        accX1[i] = (f32x4){0.f,0.f,0.f,0.f};
    }
    float4 At0[8], At1[8];   // temb rows, loaded late in X loop

    // ---- X = h_input @ W_in : 12 chunks, dbuf pipeline, counted vmcnt ----
    #pragma unroll
    for (int c = 0; c < 12; ++c) {
        if (c < 11) { STAGE8(c + 1); } else { STAGE8(12); }   // c=11 issues T chunk 0
        if (c == 2) {            // seg1 A (h[col]) -> parity 1
            #pragma unroll
            for (int ks = 0; ks < 4; ++ks) {
                Ab[1][0][2*ks]   = ld4(h + (long)ic0 * 128 + ks*32 + kb);
                Ab[1][0][2*ks+1] = ld4(h + (long)ic0 * 128 + ks*32 + kb + 4);
                Ab[1][1][2*ks]   = ld4(h + (long)ic1 * 128 + ks*32 + kb);
                Ab[1][1][2*ks+1] = ld4(h + (long)ic1 * 128 + ks*32 + kb + 4);
            }
        }
        if (c == 6) {            // seg2 A (ea|dist) -> parity 0
            #pragma unroll
            for (int ks = 0; ks < 4; ++ks) {
                const float* q0 = (ks < 2) ? (ea + (long)em0*64 + ks*32 + kb)
                                           : (dst_f + (long)em0*64 + (ks-2)*32 + kb);
                const float* q1 = (ks < 2) ? (ea + (long)em1*64 + ks*32 + kb)
                                           : (dst_f + (long)em1*64 + (ks-2)*32 + kb);
                Ab[0][0][2*ks]   = ld4(q0);
                Ab[0][0][2*ks+1] = ld4(q0 + 4);
                Ab[0][1][2*ks]   = ld4(q1);
                Ab[0][1][2*ks+1] = ld4(q1 + 4);
            }
        }
        if (c == 10) {           // temb rows for the T stage
            #pragma unroll
            for (int ks = 0; ks < 4; ++ks) {
                At0[2*ks]   = ld4(temb + (long)em0 * 128 + ks*32 + kb);
                At0[2*ks+1] = ld4(temb + (long)em0 * 128 + ks*32 + kb + 4);
                At1[2*ks]   = ld4(temb + (long)em1 * 128 + ks*32 + kb);
                At1[2*ks+1] = ld4(temb + (long)em1 * 128 + ks*32 + kb + 4);
            }
        }
        if ((c & 3) >= 2) { WAITV(24); } else { WAITV(8); }
        const int seg = c >> 2, ks = c & 3, par = seg & 1;
        bf16x8 af0 = pack8(Ab[par][0][2*ks], Ab[par][0][2*ks+1]);
        bf16x8 af1 = pack8(Ab[par][1][2*ks], Ab[par][1][2*ks+1]);
        const short* wb = &Wb[c & 1][0];
        #pragma unroll
        for (int nt = 0; nt < 8; ++nt) {
            bf16x8 b = *reinterpret_cast<const bf16x8*>(&wb[nt*512 + l*8]);
            accX0[nt] = __builtin_amdgcn_mfma_f32_16x16x32_bf16(af0, b, accX0[nt], 0, 0, 0);
            accX1[nt] = __builtin_amdgcn_mfma_f32_16x16x32_bf16(af1, b, accX1[nt], 0, 0, 0);
        }
    }

    // ---- bias + LayerNorm ----
    ln_inplace(accX0, bin, ln);
    ln_inplace(accX1, bin, ln);

    // ---- build silu(temb) fragments (compiler waits on At loads) ----
    bf16x8 ttf0[4], ttf1[4];
    #pragma unroll
    for (int ks = 0; ks < 4; ++ks) {
        float4 a0 = At0[2*ks], b0 = At0[2*ks+1];
        float4 a1 = At1[2*ks], b1v = At1[2*ks+1];
        a0.x=silu1(a0.x); a0.y=silu1(a0.y); a0.z=silu1(a0.z); a0.w=silu1(a0.w);
        b0.x=silu1(b0.x); b0.y=silu1(b0.y); b0.z=silu1(b0.z); b0.w=silu1(b0.w);
        a1.x=silu1(a1.x); a1.y=silu1(a1.y); a1.z=silu1(a1.z); a1.w=silu1(a1.w);
        b1v.x=silu1(b1v.x); b1v.y=silu1(b1v.y); b1v.z=silu1(b1v.z); b1v.w=silu1(b1v.w);
        ttf0[ks] = pack8(a0, b0);
        ttf1[ks] = pack8(a1, b1v);
    }

    // ---- T stage: 8 chunks (4 scale, 4 shift), FiLM applied inline ----
    #pragma unroll
    for (int t = 0; t < 8; ++t) {
        const int p = 12 + t;
        if (t < 7) { STAGE8(p + 1); } else { STAGE8(20); }   // t=7 issues W1 chunk 0
        WAITV(8);
        const short* wb = &Wb[p & 1][0];
        #pragma unroll
        for (int jj = 0; jj < 2; ++jj) {
            f32x4 t0 = (f32x4){0.f,0.f,0.f,0.f};
            f32x4 t1 = (f32x4){0.f,0.f,0.f,0.f};
            #pragma unroll
            for (int ks = 0; ks < 4; ++ks) {
                bf16x8 b = *reinterpret_cast<const bf16x8*>(&wb[(jj*4+ks)*512 + l*8]);
                t0 = __builtin_amdgcn_mfma_f32_16x16x32_bf16(ttf0[ks], b, t0, 0, 0, 0);
                t1 = __builtin_amdgcn_mfma_f32_16x16x32_bf16(ttf1[ks], b, t1, 0, 0, 0);
            }
            if (t < 4) {
                const int jx = 2*t + jj;
                float bsc = btime[128 + (jx<<4) + ln];
                #pragma unroll
                for (int r = 0; r < 4; ++r) {
                    accX0[jx][r] *= (1.f + t0[r] + bsc);
                    accX1[jx][r] *= (1.f + t1[r] + bsc);
                }
            } else {
                const int jx = 2*(t-4) + jj;
                float bsh = btime[(jx<<4) + ln];
                #pragma unroll
                for (int r = 0; r < 4; ++r) {
                    accX0[jx][r] += t0[r] + bsh;
                    accX1[jx][r] += t1[r] + bsh;
                }
            }
        }
    }

    // ---- transpose inv (C-layout -> A-layout) through LDS (wave-local) ----
    #pragma unroll
    for (int nt = 0; nt < 8; ++nt)
        #pragma unroll
        for (int r = 0; r < 4; ++r) {
            Tb[((lg<<2) + r)*136      + (nt<<4) + ln] = f2bf(accX0[nt][r]);
            Tb[(16 + (lg<<2) + r)*136 + (nt<<4) + ln] = f2bf(accX1[nt][r]);
        }
    bf16x8 iaf0[4], iaf1[4];
    #pragma unroll
    for (int ks = 0; ks < 4; ++ks) {
        iaf0[ks] = *reinterpret_cast<const bf16x8*>(&Tb[ln*136      + (ks<<5) + kb]);
        iaf1[ks] = *reinterpret_cast<const bf16x8*>(&Tb[(16+ln)*136 + (ks<<5) + kb]);
    }

    // ---- W1 stage: 4 chunks ----
    f32x4 accY0[8], accY1[8];
    #pragma unroll
    for (int i = 0; i < 8; ++i) {
        accY0[i] = (f32x4){0.f,0.f,0.f,0.f};
        accY1[i] = (f32x4){0.f,0.f,0.f,0.f};
    }
    #pragma unroll
    for (int u = 0; u < 4; ++u) {
        const int p = 20 + u;
        if (u < 3) { STAGE8(p + 1); WAITV(8); }
        else       { STAGE4(24);    WAITV(4); }   // last: W2 chunk (4 frags)
        const short* wb = &Wb[p & 1][0];
        #pragma unroll
        for (int s = 0; s < 2; ++s) {
            const int nt = 2*u + s;
            #pragma unroll
            for (int ks = 0; ks < 4; ++ks) {
                bf16x8 b = *reinterpret_cast<const bf16x8*>(&wb[(s*4+ks)*512 + l*8]);
                accY0[nt] = __builtin_amdgcn_mfma_f32_16x16x32_bf16(iaf0[ks], b, accY0[nt], 0, 0, 0);
                accY1[nt] = __builtin_amdgcn_mfma_f32_16x16x32_bf16(iaf1[ks], b, accY1[nt], 0, 0, 0);
            }
        }
    }

    // ---- silu + transpose back ----
    #pragma unroll
    for (int nt = 0; nt < 8; ++nt) {
        float bv = b1[(nt<<4) + ln];
        #pragma unroll
        for (int r = 0; r < 4; ++r) {
            Tb[((lg<<2) + r)*136      + (nt<<4) + ln] = f2bf(silu1(accY0[nt][r] + bv));
            Tb[(16 + (lg<<2) + r)*136 + (nt<<4) + ln] = f2bf(silu1(accY1[nt][r] + bv));
        }
    }
    bf16x8 yaf0[4], yaf1[4];
    #pragma unroll
    for (int ks = 0; ks < 4; ++ks) {
        yaf0[ks] = *reinterpret_cast<const bf16x8*>(&Tb[ln*136      + (ks<<5) + kb]);
        yaf1[ks] = *reinterpret_cast<const bf16x8*>(&Tb[(16+ln)*136 + (ks<<5) + kb]);
    }

    // ---- W2 stage (chunk 24, parity 0) ----
    WAITV(0);
    f32x4 accZ0 = (f32x4){0.f,0.f,0.f,0.f};
    f32x4 accZ1 = (f32x4){0.f,0.f,0.f,0.f};
    {
        const short* wb = &Wb[0][0];
        #pragma unroll
        for (int ks = 0; ks < 4; ++ks) {
            bf16x8 b = *reinterpret_cast<const bf16x8*>(&wb[ks*512 + l*8]);
            accZ0 = __builtin_amdgcn_mfma_f32_16x16x32_bf16(yaf0[ks], b, accZ0, 0, 0, 0);
            accZ1 = __builtin_amdgcn_mfma_f32_16x16x32_bf16(yaf1[ks], b, accZ1, 0, 0, 0);
        }
    }

    // ---- tanh, head-mean, atomic scatter ----
    #pragma unroll
    for (int r = 0; r < 4; ++r) {
        {
            int   m = (lg<<2) + r;
            float z = tanh1(accZ0[r]);
            float wt = (ln == 0) ? 1.0f : ((ln < 4) ? sAdj[ln-1][m] : 0.0f);
            float v = z * wt;
            v += __shfl_xor(v, 1);
            v += __shfl_xor(v, 2);
            v += __shfl_xor(v, 4);
            v += __shfl_xor(v, 8);
            float s = v * 0.25f;
            if (ln < 3) atomicAdd(&out[(long)sIr[m]*3 + ln], sCd[ln][m] * s);
        }
        {
            int   m = 16 + (lg<<2) + r;
            float z = tanh1(accZ1[r]);
            float wt = (ln == 0) ? 1.0f : ((ln < 4) ? sAdj[ln-1][m] : 0.0f);
            float v = z * wt;
            v += __shfl_xor(v, 1);
            v += __shfl_xor(v, 2);
            v += __shfl_xor(v, 4);
            v += __shfl_xor(v, 8);
            float s = v * 0.25f;
            if (ln < 3) atomicAdd(&out[(long)sIr[m]*3 + ln], sCd[ln][m] * s);
        }
    }
    #undef STAGE8
    #undef STAGE4
}

extern "C" void kernel_launch(void* const* d_in, const int* in_sizes, int n_in,
                              void* d_out, int out_size, void* d_ws, size_t ws_size,
                              hipStream_t stream) {
    const float* h     = (const float*)d_in[0];
    const float* pos   = (const float*)d_in[1];
    const float* ea    = (const float*)d_in[2];
    const float* dist  = (const float*)d_in[3];
    const float* temb  = (const float*)d_in[4];
    const float* adj   = (const float*)d_in[5];
    const float* Wt    = (const float*)d_in[6];
    const float* bt    = (const float*)d_in[7];
    const float* Win   = (const float*)d_in[8];
    const float* bin   = (const float*)d_in[9];
    const float* W1    = (const float*)d_in[10];
    const float* b1    = (const float*)d_in[11];
    const float* W2    = (const float*)d_in[12];
    const float* cs    = (const float*)d_in[13];
    const int*   ei    = (const int*)d_in[14];
    float*       out   = (float*)d_out;
    short*       ws    = (short*)d_ws;

    pack_weights_kernel<<<(196*512 + 255) / 256, 256, 0, stream>>>(Wt, Win, W1, W2, ws);
    hipMemcpyAsync(out, pos, (size_t)out_size * sizeof(float),
                   hipMemcpyDeviceToDevice, stream);
    edge_kernel<<<E_EDGES / 32, 64, 0, stream>>>(h, pos, ea, dist, temb, adj,
                                                 bt, bin, b1, cs, ei, ws, out);
}